// Round 1
// baseline (367.305 us; speedup 1.0000x reference)
//
#include <hip/hip_runtime.h>
#include <hip/hip_bf16.h>

typedef __bf16 bf16x8 __attribute__((ext_vector_type(8)));
typedef __bf16 bf16x4 __attribute__((ext_vector_type(4)));
typedef float f32x4 __attribute__((ext_vector_type(4)));

// Problem constants
#define S_LEN 2048
#define D_DIM 128
#define BH 32            // B*H
#define BM 128           // q rows per block
#define BN 64            // keys per k-tile
#define MI 2             // 16-row MFMA m-tiles per wave (wave covers 32 q rows)
#define NWAVE 4
#define SCALE 0.08838834764831845f  // 1/sqrt(128)

__global__ __launch_bounds__(256, 2)
void fa_fwd_kernel(const float* __restrict__ Qg, const float* __restrict__ Kg,
                   const float* __restrict__ Vg, float* __restrict__ Og) {
    // LDS: K tile [k][d] (+8 pad), V tile transposed+swizzled [d][k], P per-wave [q][k]
    __shared__ __bf16 Klds[BN][D_DIM + 8];        // 64 x 136 = 17408 B
    __shared__ __bf16 Vlds[D_DIM][BN + 8];        // 128 x 72  = 18432 B
    __shared__ __bf16 Plds[NWAVE][32][BN + 8];    // 4 x 32 x 72 = 18432 B

    const int bh   = blockIdx.x & (BH - 1);   // head-minor: same head -> same XCD (idx%8)
    const int qt   = blockIdx.x >> 5;         // 0..15
    const int tid  = threadIdx.x;
    const int wave = tid >> 6;
    const int lane = tid & 63;
    const int quad = lane >> 4;
    const int m16  = lane & 15;

    const float* Qh = Qg + bh * (S_LEN * D_DIM);
    const float* Kh = Kg + bh * (S_LEN * D_DIM);
    const float* Vh = Vg + bh * (S_LEN * D_DIM);
    float*       Oh = Og + bh * (S_LEN * D_DIM);

    const int qrow_base = qt * BM + wave * 32;

    // ---- Load Q fragments once (A-layout: A[m=lane&15][k=quad*8+j]), fold in scale ----
    bf16x8 qf[MI][4];
#pragma unroll
    for (int mi = 0; mi < MI; ++mi) {
        const float* qp = Qh + (qrow_base + mi * 16 + m16) * D_DIM;
#pragma unroll
        for (int ks = 0; ks < 4; ++ks) {
            const float4 a = *(const float4*)(qp + ks * 32 + quad * 8);
            const float4 b = *(const float4*)(qp + ks * 32 + quad * 8 + 4);
            bf16x8 f;
            f[0] = (__bf16)(a.x * SCALE); f[1] = (__bf16)(a.y * SCALE);
            f[2] = (__bf16)(a.z * SCALE); f[3] = (__bf16)(a.w * SCALE);
            f[4] = (__bf16)(b.x * SCALE); f[5] = (__bf16)(b.y * SCALE);
            f[6] = (__bf16)(b.z * SCALE); f[7] = (__bf16)(b.w * SCALE);
            qf[mi][ks] = f;
        }
    }

    // ---- Accumulators / online-softmax state ----
    f32x4 o_acc[MI][8];
#pragma unroll
    for (int mi = 0; mi < MI; ++mi)
#pragma unroll
        for (int nt = 0; nt < 8; ++nt) {
            o_acc[mi][nt][0] = 0.f; o_acc[mi][nt][1] = 0.f;
            o_acc[mi][nt][2] = 0.f; o_acc[mi][nt][3] = 0.f;
        }
    float m_st[MI][4], l_st[MI][4];
#pragma unroll
    for (int mi = 0; mi < MI; ++mi)
#pragma unroll
        for (int r = 0; r < 4; ++r) { m_st[mi][r] = -1e30f; l_st[mi][r] = 0.f; }

    // ---- Main loop over key tiles ----
    for (int kt = 0; kt < S_LEN / BN; ++kt) {
        __syncthreads();  // previous iteration's LDS consumers done

        // Stage K tile: [k][d], row-major, vectorized 8B writes
        {
            const float* kg = Kh + kt * BN * D_DIM;
#pragma unroll
            for (int i = 0; i < 8; ++i) {
                const int idx = tid + i * 256;      // 0..2047 float4 chunks
                const int r = idx >> 5, c4 = idx & 31;
                const float4 v = *(const float4*)(kg + r * D_DIM + c4 * 4);
                bf16x4 w;
                w[0] = (__bf16)v.x; w[1] = (__bf16)v.y;
                w[2] = (__bf16)v.z; w[3] = (__bf16)v.w;
                *(bf16x4*)&Klds[r][c4 * 4] = w;
            }
            // Stage V transposed: Vlds[d][(kb ^ (d&7))*8 + (k&7)] = V[k][d]
            const float* vg = Vh + kt * BN * D_DIM;
            const int c4 = tid & 31, rp0 = tid >> 5;
#pragma unroll
            for (int i = 0; i < 4; ++i) {
                const int r = (rp0 + i * 8) * 2;     // even row in 0..62
                const float4 v0 = *(const float4*)(vg + r * D_DIM + c4 * 4);
                const float4 v1 = *(const float4*)(vg + (r + 1) * D_DIM + c4 * 4);
                const float* p0 = reinterpret_cast<const float*>(&v0);
                const float* p1 = reinterpret_cast<const float*>(&v1);
                const int kb = r >> 3, jj = r & 7;
#pragma unroll
                for (int j = 0; j < 4; ++j) {
                    const int d = c4 * 4 + j;
                    union { __bf16 h[2]; unsigned int u; } pk;
                    pk.h[0] = (__bf16)p0[j]; pk.h[1] = (__bf16)p1[j];
                    *(unsigned int*)&Vlds[d][((kb ^ (d & 7)) << 3) + jj] = pk.u;
                }
            }
        }
        __syncthreads();

        // ---- S = Q K^T (scaled) ----
        f32x4 sacc[MI][4];
#pragma unroll
        for (int mi = 0; mi < MI; ++mi)
#pragma unroll
            for (int nt = 0; nt < 4; ++nt) {
                sacc[mi][nt][0] = 0.f; sacc[mi][nt][1] = 0.f;
                sacc[mi][nt][2] = 0.f; sacc[mi][nt][3] = 0.f;
            }
#pragma unroll
        for (int ks = 0; ks < 4; ++ks)
#pragma unroll
            for (int nt = 0; nt < 4; ++nt) {
                // B-layout: B[k=quad*8+j][n=lane&15] = K[nt*16+m16][d]
                const bf16x8 kf = *(const bf16x8*)&Klds[nt * 16 + m16][ks * 32 + quad * 8];
#pragma unroll
                for (int mi = 0; mi < MI; ++mi)
                    sacc[mi][nt] = __builtin_amdgcn_mfma_f32_16x16x32_bf16(
                        qf[mi][ks], kf, sacc[mi][nt], 0, 0, 0);
            }

        // ---- online softmax (C-layout rows: quad*4+reg) ----
#pragma unroll
        for (int mi = 0; mi < MI; ++mi) {
            float mx[4];
#pragma unroll
            for (int r = 0; r < 4; ++r)
                mx[r] = fmaxf(fmaxf(sacc[mi][0][r], sacc[mi][1][r]),
                              fmaxf(sacc[mi][2][r], sacc[mi][3][r]));
#pragma unroll
            for (int xm = 1; xm <= 8; xm <<= 1)
#pragma unroll
                for (int r = 0; r < 4; ++r)
                    mx[r] = fmaxf(mx[r], __shfl_xor(mx[r], xm, 64));
            float alpha[4];
#pragma unroll
            for (int r = 0; r < 4; ++r) {
                const float mnew = fmaxf(m_st[mi][r], mx[r]);
                alpha[r] = __expf(m_st[mi][r] - mnew);
                m_st[mi][r] = mnew;
            }
            float p[4][4], rs[4];
#pragma unroll
            for (int nt = 0; nt < 4; ++nt)
#pragma unroll
                for (int r = 0; r < 4; ++r)
                    p[nt][r] = __expf(sacc[mi][nt][r] - m_st[mi][r]);
#pragma unroll
            for (int r = 0; r < 4; ++r)
                rs[r] = (p[0][r] + p[1][r]) + (p[2][r] + p[3][r]);
#pragma unroll
            for (int xm = 1; xm <= 8; xm <<= 1)
#pragma unroll
                for (int r = 0; r < 4; ++r)
                    rs[r] += __shfl_xor(rs[r], xm, 64);
#pragma unroll
            for (int r = 0; r < 4; ++r)
                l_st[mi][r] = l_st[mi][r] * alpha[r] + rs[r];
            // rescale O accumulator
#pragma unroll
            for (int nt = 0; nt < 8; ++nt)
#pragma unroll
                for (int r = 0; r < 4; ++r)
                    o_acc[mi][nt][r] *= alpha[r];
            // write P (C-layout) to LDS for A-layout re-read
#pragma unroll
            for (int nt = 0; nt < 4; ++nt)
#pragma unroll
                for (int r = 0; r < 4; ++r)
                    Plds[wave][mi * 16 + quad * 4 + r][nt * 16 + m16] = (__bf16)p[nt][r];
        }
        __syncthreads();  // P visible (and wave-internal write->read ordering)

        // ---- O += P V ----
#pragma unroll
        for (int ks = 0; ks < 2; ++ks) {
            bf16x8 pa[MI];
#pragma unroll
            for (int mi = 0; mi < MI; ++mi)
                pa[mi] = *(const bf16x8*)&Plds[wave][mi * 16 + m16][ks * 32 + quad * 8];
#pragma unroll
            for (int nt = 0; nt < 8; ++nt) {
                const int d = nt * 16 + m16;
                const int kb0 = ks * 4 + quad;
                const bf16x8 vf = *(const bf16x8*)&Vlds[d][((kb0 ^ (d & 7)) << 3)];
#pragma unroll
                for (int mi = 0; mi < MI; ++mi)
                    o_acc[mi][nt] = __builtin_amdgcn_mfma_f32_16x16x32_bf16(
                        pa[mi], vf, o_acc[mi][nt], 0, 0, 0);
            }
        }
    }

    // ---- epilogue: O / l ----
#pragma unroll
    for (int mi = 0; mi < MI; ++mi) {
        float inv[4];
#pragma unroll
        for (int r = 0; r < 4; ++r) inv[r] = 1.0f / l_st[mi][r];
#pragma unroll
        for (int nt = 0; nt < 8; ++nt)
#pragma unroll
            for (int r = 0; r < 4; ++r)
                Oh[(qrow_base + mi * 16 + quad * 4 + r) * D_DIM + nt * 16 + m16] =
                    o_acc[mi][nt][r] * inv[r];
    }
}

extern "C" void kernel_launch(void* const* d_in, const int* in_sizes, int n_in,
                              void* d_out, int out_size, void* d_ws, size_t ws_size,
                              hipStream_t stream) {
    const float* Q = (const float*)d_in[0];
    const float* K = (const float*)d_in[1];
    const float* V = (const float*)d_in[2];
    float* O = (float*)d_out;
    dim3 grid(BH * (S_LEN / BM));  // 32 * 16 = 512 blocks
    fa_fwd_kernel<<<grid, 256, 0, stream>>>(Q, K, V, O);
}

// Round 2
// 295.793 us; speedup vs baseline: 1.2418x; 1.2418x over previous
//
#include <hip/hip_runtime.h>
#include <hip/hip_bf16.h>

typedef __bf16 bf16x8 __attribute__((ext_vector_type(8)));
typedef float f32x4 __attribute__((ext_vector_type(4)));

// Problem constants
#define S_LEN 2048
#define D_DIM 128
#define BH 32            // B*H
#define BM 128           // q rows per block
#define BN 64            // keys per k-tile
#define NWAVE 8          // 512 threads; each wave owns 16 q rows
// 1/sqrt(128) * log2(e): scores land pre-multiplied by log2e so exp() becomes raw v_exp_f32 (exp2)
#define QSCALE (0.08838834764831845f * 1.4426950408889634f)

__global__ __launch_bounds__(512, 4)  // cap VGPR<=128 so 2 blocks/CU (16 waves) fit
void fa_fwd_kernel(const float* __restrict__ Qg, const float* __restrict__ Kg,
                   const float* __restrict__ Vg, float* __restrict__ Og) {
    // K: [k][d] natural (+8 pad). V: transposed [d][k] with column-block swizzle
    //   element(k,d) stored at col ((k>>3) ^ ((d>>3)&7))*8 + (k&7)
    //   -> write banks 2-way max (was 16-way with the old (d&7) swizzle), reads contiguous 16B.
    __shared__ __bf16 Klds[BN][D_DIM + 8];        // 17408 B
    __shared__ __bf16 Vlds[D_DIM][BN + 8];        // 18432 B
    __shared__ __bf16 Plds[NWAVE][16][BN + 8];    // 18432 B   (total 54272 -> 2 blocks/CU)

    const int bh   = blockIdx.x & (BH - 1);   // head-minor: same head -> same XCD
    const int qt   = blockIdx.x >> 5;
    const int tid  = threadIdx.x;
    const int wave = tid >> 6;
    const int lane = tid & 63;
    const int quad = lane >> 4;
    const int m16  = lane & 15;

    const float* Qh = Qg + bh * (S_LEN * D_DIM);
    const float* Kh = Kg + bh * (S_LEN * D_DIM);
    const float* Vh = Vg + bh * (S_LEN * D_DIM);
    float*       Oh = Og + bh * (S_LEN * D_DIM);

    const int qrow_base = qt * BM + wave * 16;

    // ---- Q fragments (A-layout: A[m=lane&15][k=quad*8+j]), scale*log2e folded in ----
    bf16x8 qf[4];
#pragma unroll
    for (int ks = 0; ks < 4; ++ks) {
        const float* qp = Qh + (qrow_base + m16) * D_DIM + ks * 32 + quad * 8;
        const float4 a = *(const float4*)(qp);
        const float4 b = *(const float4*)(qp + 4);
        bf16x8 f;
        f[0] = (__bf16)(a.x * QSCALE); f[1] = (__bf16)(a.y * QSCALE);
        f[2] = (__bf16)(a.z * QSCALE); f[3] = (__bf16)(a.w * QSCALE);
        f[4] = (__bf16)(b.x * QSCALE); f[5] = (__bf16)(b.y * QSCALE);
        f[6] = (__bf16)(b.z * QSCALE); f[7] = (__bf16)(b.w * QSCALE);
        qf[ks] = f;
    }

    f32x4 o_acc[8];
#pragma unroll
    for (int nt = 0; nt < 8; ++nt) {
        o_acc[nt][0] = 0.f; o_acc[nt][1] = 0.f; o_acc[nt][2] = 0.f; o_acc[nt][3] = 0.f;
    }
    float m_st[4], l_st[4];
#pragma unroll
    for (int r = 0; r < 4; ++r) { m_st[r] = -1e30f; l_st[r] = 0.f; }

    for (int kt = 0; kt < S_LEN / BN; ++kt) {
        __syncthreads();  // prior iteration's K/V consumers done

        // ---- stage K tile: each thread converts 8 contiguous floats -> one 16B LDS store ----
        {
            const float* kg = Kh + kt * BN * D_DIM;
#pragma unroll
            for (int i = 0; i < 2; ++i) {
                const int idx = tid + i * 512;          // 0..1023 chunks of 8
                const int r = idx >> 4, c8 = idx & 15;
                const float4 a = *(const float4*)(kg + r * D_DIM + c8 * 8);
                const float4 b = *(const float4*)(kg + r * D_DIM + c8 * 8 + 4);
                bf16x8 w;
                w[0] = (__bf16)a.x; w[1] = (__bf16)a.y; w[2] = (__bf16)a.z; w[3] = (__bf16)a.w;
                w[4] = (__bf16)b.x; w[5] = (__bf16)b.y; w[6] = (__bf16)b.z; w[7] = (__bf16)b.w;
                *(bf16x8*)&Klds[r][c8 * 8] = w;
            }
            // ---- stage V transposed with corrected swizzle ----
            const float* vg = Vh + kt * BN * D_DIM;
            const int c4 = tid & 31, rp = tid >> 5;     // rp 0..15
#pragma unroll
            for (int i = 0; i < 2; ++i) {
                const int r = (rp + i * 16) * 2;        // even row 0..62
                const float4 v0 = *(const float4*)(vg + r * D_DIM + c4 * 4);
                const float4 v1 = *(const float4*)(vg + (r + 1) * D_DIM + c4 * 4);
                const float* p0 = reinterpret_cast<const float*>(&v0);
                const float* p1 = reinterpret_cast<const float*>(&v1);
                const int kb = r >> 3, jj = r & 7;
#pragma unroll
                for (int j = 0; j < 4; ++j) {
                    const int d = c4 * 4 + j;
                    union { __bf16 h[2]; unsigned int u; } pk;
                    pk.h[0] = (__bf16)p0[j]; pk.h[1] = (__bf16)p1[j];
                    *(unsigned int*)&Vlds[d][((kb ^ ((d >> 3) & 7)) << 3) + jj] = pk.u;
                }
            }
        }
        __syncthreads();

        // ---- S = (Q*scale*log2e) K^T ----
        f32x4 sacc[4];
#pragma unroll
        for (int nt = 0; nt < 4; ++nt) {
            sacc[nt][0] = 0.f; sacc[nt][1] = 0.f; sacc[nt][2] = 0.f; sacc[nt][3] = 0.f;
        }
#pragma unroll
        for (int ks = 0; ks < 4; ++ks)
#pragma unroll
            for (int nt = 0; nt < 4; ++nt) {
                const bf16x8 kf = *(const bf16x8*)&Klds[nt * 16 + m16][ks * 32 + quad * 8];
                sacc[nt] = __builtin_amdgcn_mfma_f32_16x16x32_bf16(qf[ks], kf, sacc[nt], 0, 0, 0);
            }

        // ---- online softmax in exp2 domain (C-rows: quad*4+r) ----
        {
            float mx[4];
#pragma unroll
            for (int r = 0; r < 4; ++r)
                mx[r] = fmaxf(fmaxf(sacc[0][r], sacc[1][r]), fmaxf(sacc[2][r], sacc[3][r]));
#pragma unroll
            for (int xm = 1; xm <= 8; xm <<= 1)
#pragma unroll
                for (int r = 0; r < 4; ++r)
                    mx[r] = fmaxf(mx[r], __shfl_xor(mx[r], xm, 64));
            float alpha[4], rs[4];
#pragma unroll
            for (int r = 0; r < 4; ++r) {
                const float mnew = fmaxf(m_st[r], mx[r]);
                alpha[r] = __builtin_amdgcn_exp2f(m_st[r] - mnew);
                m_st[r] = mnew;
                rs[r] = 0.f;
            }
#pragma unroll
            for (int nt = 0; nt < 4; ++nt) {
#pragma unroll
                for (int r = 0; r < 4; ++r) {
                    const float p = __builtin_amdgcn_exp2f(sacc[nt][r] - m_st[r]);
                    rs[r] += p;
                    Plds[wave][quad * 4 + r][nt * 16 + m16] = (__bf16)p;
                }
            }
#pragma unroll
            for (int xm = 1; xm <= 8; xm <<= 1)
#pragma unroll
                for (int r = 0; r < 4; ++r)
                    rs[r] += __shfl_xor(rs[r], xm, 64);
#pragma unroll
            for (int r = 0; r < 4; ++r)
                l_st[r] = l_st[r] * alpha[r] + rs[r];
#pragma unroll
            for (int nt = 0; nt < 8; ++nt)
#pragma unroll
                for (int r = 0; r < 4; ++r)
                    o_acc[nt][r] *= alpha[r];
        }
        __syncthreads();  // P visible

        // ---- O += P V ----
#pragma unroll
        for (int ks = 0; ks < 2; ++ks) {
            const bf16x8 pa = *(const bf16x8*)&Plds[wave][m16][ks * 32 + quad * 8];
#pragma unroll
            for (int nt = 0; nt < 8; ++nt) {
                const int d = nt * 16 + m16;
                const bf16x8 vf =
                    *(const bf16x8*)&Vlds[d][((ks * 4 + quad) ^ ((d >> 3) & 7)) << 3];
                o_acc[nt] = __builtin_amdgcn_mfma_f32_16x16x32_bf16(pa, vf, o_acc[nt], 0, 0, 0);
            }
        }
    }

    // ---- epilogue ----
    float inv[4];
#pragma unroll
    for (int r = 0; r < 4; ++r) inv[r] = 1.0f / l_st[r];
#pragma unroll
    for (int nt = 0; nt < 8; ++nt)
#pragma unroll
        for (int r = 0; r < 4; ++r)
            Oh[(qrow_base + quad * 4 + r) * D_DIM + nt * 16 + m16] = o_acc[nt][r] * inv[r];
}

extern "C" void kernel_launch(void* const* d_in, const int* in_sizes, int n_in,
                              void* d_out, int out_size, void* d_ws, size_t ws_size,
                              hipStream_t stream) {
    const float* Q = (const float*)d_in[0];
    const float* K = (const float*)d_in[1];
    const float* V = (const float*)d_in[2];
    float* O = (float*)d_out;
    dim3 grid(BH * (S_LEN / BM));  // 512 blocks -> 2 blocks/CU, 16 waves/CU
    fa_fwd_kernel<<<grid, 512, 0, stream>>>(Q, K, V, O);
}